// Round 13
// baseline (266.645 us; speedup 1.0000x reference)
//
#include <hip/hip_runtime.h>

typedef __bf16 bf16_t;
typedef __bf16 bf16x8 __attribute__((ext_vector_type(8)));
typedef float f32x16 __attribute__((ext_vector_type(16)));
typedef unsigned int u32;

#define CTOT 320
#define NPIX 32768  // 8*64*64

// global -> LDS direct DMA, 16 B per lane; LDS dest = wave-uniform base + lane*16
__device__ __forceinline__ void gload16(const void* g, void* l) {
  __builtin_amdgcn_global_load_lds((const __attribute__((address_space(1))) u32*)g,
                                   (__attribute__((address_space(3))) u32*)l, 16, 0, 0);
}

// ---------- merged prep: y transpose (+packed), 9 weight transposes, zero page
struct PrepParams {
  const float* y;
  bf16_t *yt, *ytp, *wt;
  const float* w[9];
  int IC[9], OC[9], OCp[9], wtoff[9], jst[9];
  uint4* zp;
};

__global__ __launch_bounds__(256) void k_prep(PrepParams Q) {
  int blk = blockIdx.x, tid = threadIdx.x;
  if (blk >= 2560) {
    int wb = blk - 2560;
    if (wb >= 572) { if (tid < 64) Q.zp[tid] = uint4{0u, 0u, 0u, 0u}; return; }
    int ci = 0;
#pragma unroll
    for (int i = 1; i < 9; ++i) if (wb >= Q.jst[i]) ci = i;
    int IC = Q.IC[ci], OCp = Q.OCp[ci], OC = Q.OC[ci];
    int idx = (wb - Q.jst[ci]) * 256 + tid;
    if (idx >= OCp * IC) return;
    int oc = idx / IC, ic = idx - oc * IC;
    bool valid = (oc < OC);
    const float* src = Q.w[ci] + (size_t)(oc * IC + ic) * 25;
    bf16_t* dst = Q.wt + Q.wtoff[ci];
    int icg = ic >> 3, ie = ic & 7;
#pragma unroll
    for (int t = 0; t < 25; ++t) {
      float v = valid ? src[t] : 0.0f;
      dst[(size_t)((t * (IC >> 3) + icg) * OCp + oc) * 8 + ie] = (bf16_t)v;
    }
    return;
  }
  __shared__ bf16_t T[64][72];
  int c0 = (blk % 5) * 64;
  int bh = blk / 5;
  int b = bh >> 6, h = bh & 63;
  {
    int c = tid >> 2, w0 = (tid & 3) << 4;
    const float* src = Q.y + (size_t)(b * CTOT + c0 + c) * 4096 + (h << 6) + w0;
#pragma unroll
    for (int j = 0; j < 16; j += 4) {
      float4 v = *(const float4*)(src + j);
      T[c][w0 + j + 0] = (bf16_t)v.x;
      T[c][w0 + j + 1] = (bf16_t)v.y;
      T[c][w0 + j + 2] = (bf16_t)v.z;
      T[c][w0 + j + 3] = (bf16_t)v.w;
    }
  }
  __syncthreads();
  {
    int w = tid >> 2, cq = (tid & 3) << 4;
    union { uint4 v; bf16_t b[8]; } u0, u1;
#pragma unroll
    for (int j = 0; j < 8; ++j) { u0.b[j] = T[cq + j][w]; u1.b[j] = T[cq + 8 + j][w]; }
    bf16_t* dst = Q.yt + (size_t)((bh << 6) | w) * CTOT + c0 + cq;
    *(uint4*)dst = u0.v;
    *(uint4*)(dst + 8) = u1.v;
  }
  if (tid < 128) {  // packed even-checkerboard copy: w = 2j + (h&1)
    int j = tid >> 2, cq = (tid & 3) << 4;
    int w = (j << 1) + (h & 1);
    union { uint4 v; bf16_t b[8]; } u0, u1;
#pragma unroll
    for (int k = 0; k < 8; ++k) { u0.b[k] = T[cq + k][w]; u1.b[k] = T[cq + 8 + k][w]; }
    bf16_t* dst = Q.ytp + (size_t)((bh << 5) + j) * CTOT + c0 + cq;
    *(uint4*)dst = u0.v;
    *(uint4*)(dst + 8) = u1.v;
  }
}

// ---------- main conv: 32x32x16 MFMA, K-chunk=16, A (weights) loaded
// global->VGPR (L2-hot, compiler-counted vmcnt waits); LDS holds only the
// double-buffered input tile (DMA-staged). 1 raw barrier per chunk.
struct ConvDesc {
  const float* bias;
  int out_off, wt_off;
  int IC, OC, OCp, chs, masked, job_start;
};
struct MainParams {
  const bf16_t* yt;
  const bf16_t* ytp;
  const bf16_t* wt;
  const bf16_t* zp;
  float* out;
  ConvDesc cv[9];
};

template <bool MASKED>
__device__ __forceinline__ void conv_run(const ConvDesc cd, const MainParams& P,
                                         int local, bf16_t* S) {
  constexpr int NT   = MASKED ? 12 : 25;
  constexpr int P1   = MASKED ? 4 : 5;       // taps before the Sin-issue point
  constexpr int COLS = MASKED ? 36 : 68;
  constexpr int REAL = MASKED ? 432 : 544;   // real slots (12x36 / 8x68)
  constexpr int NSG  = MASKED ? 7 : 9;       // 64-slot DMA groups per plane
  constexpr int SPL  = NSG * 512;            // plane stride (el)
  constexpr int SINB = 2 * SPL;              // one Sin buffer (2 icg planes)

  // unmasked: block = 64 oc x 256 px (4 rows); masked: 64 oc x 8 out-rows
  int mb = MASKED ? (local >> 6) : (local >> 7);
  int nb = local & (MASKED ? 63 : 127);
  int b  = MASKED ? (nb >> 3) : (nb >> 4);
  int hblk = MASKED ? ((nb & 7) << 3) : ((nb & 15) << 2);
  int tid = threadIdx.x, lane = tid & 63, wid = tid >> 6;
  int l31 = lane & 31, kq = lane >> 5;

  int octmax = (cd.OC - (mb << 6)) >> 5; if (octmax > 2) octmax = 2;

  f32x16 acc00 = {}, acc01 = {}, acc10 = {}, acc11 = {};

  int bofs = kq * SPL + (MASKED ? (((wid << 1) * 36 + 1 + l31) * 8)
                                : ((wid * 68 + l31) * 8));

  const bf16_t* wtc = P.wt + cd.wt_off;
  int icgs = cd.IC >> 3;
  int nchunks = cd.IC >> 4;
  size_t ocp8 = (size_t)cd.OCp << 3;           // el per icg plane of one tap
  size_t wstride = (size_t)icgs * ocp8;        // el per tap
  const bf16_t* wbase = wtc + (size_t)(kq * cd.OCp + (mb << 6) + l31) * 8;

  auto stage_sin = [&](int cb, int buf) {
    int ic0 = cb << 4;
    for (int g = wid; g < 2 * NSG; g += 4) {
      int p = (g >= NSG) ? 1 : 0;
      int gi = g - p * NSG;
      int s = (gi << 6) + lane;
      int rr = s / COLS, cc = s - rr * COLS;
      int h = hblk + rr - 2;
      const bf16_t* gp;
      if (!MASKED) {
        int w = cc - 2;
        bool inb = (s < REAL) && ((unsigned)h < 64u) && ((unsigned)w < 64u);
        gp = inb ? (P.yt + (size_t)((((b << 6) + (h & 63)) << 6) | (w & 63)) * CTOT
                        + cd.chs + ic0 + (p << 3))
                 : P.zp;
      } else {
        int j = cc - 1;
        bool inb = (s < REAL) && ((unsigned)h < 64u) && ((unsigned)j < 32u);
        gp = inb ? (P.ytp + (size_t)((((b << 6) + (h & 63)) << 5) + (j & 31)) * CTOT
                         + cd.chs + ic0 + (p << 3))
                 : P.zp;
      }
      gload16(gp, S + buf * SINB + p * SPL + (gi << 9));
    }
  };

#define TAP_ONE(TI)                                                             \
    {                                                                           \
      int tap_ = MASKED ? (2 * (TI) + 1) : (TI);                                \
      int dy_ = tap_ / 5, dx_ = tap_ % 5;                                       \
      const bf16_t* ap_ = wa + (size_t)tap_ * wstride;                          \
      bf16x8 af0 = *(const bf16x8*)ap_;                                         \
      bf16x8 bf0, bf1;                                                          \
      if (!MASKED) {                                                            \
        int toff_ = (dy_ * 68 + dx_) * 8;                                       \
        bf0 = *(const bf16x8*)(Sn + bofs + toff_);                              \
        bf1 = *(const bf16x8*)(Sn + bofs + toff_ + 256);                        \
      } else {                                                                  \
        int j0_ = (dx_ - 1 - (dy_ & 1)) / 2;                                    \
        int j1_ = (dx_ - 2 - ((dy_ + 1) & 1)) / 2;                              \
        bf0 = *(const bf16x8*)(Sn + bofs + (dy_ * 36 + j0_) * 8);               \
        bf1 = *(const bf16x8*)(Sn + bofs + ((dy_ + 1) * 36 + j1_) * 8);         \
      }                                                                         \
      acc00 = __builtin_amdgcn_mfma_f32_32x32x16_bf16(af0, bf0, acc00, 0, 0, 0);\
      acc01 = __builtin_amdgcn_mfma_f32_32x32x16_bf16(af0, bf1, acc01, 0, 0, 0);\
      if (octmax > 1) {                                                         \
        bf16x8 af1 = *(const bf16x8*)(ap_ + 256);                               \
        acc10 = __builtin_amdgcn_mfma_f32_32x32x16_bf16(af1, bf0, acc10, 0,0,0);\
        acc11 = __builtin_amdgcn_mfma_f32_32x32x16_bf16(af1, bf1, acc11, 0,0,0);\
      }                                                                         \
    }

  stage_sin(0, 0);
  for (int cb = 0; cb < nchunks; ++cb) {
    const bf16_t* Sn = S + (cb & 1) * SINB;
    const bf16_t* wa = wbase + (size_t)(cb << 1) * ocp8;
    // raw barrier: manual drain of this wave's DMA queue, no compiler vmcnt(0)
    asm volatile("s_waitcnt vmcnt(0)" ::: "memory");
    __builtin_amdgcn_sched_barrier(0);
    __builtin_amdgcn_s_barrier();
    __builtin_amdgcn_sched_barrier(0);
    __builtin_amdgcn_s_setprio(1);
#pragma unroll
    for (int s_ = 0; s_ < P1; ++s_) TAP_ONE(s_)
    __builtin_amdgcn_s_setprio(0);
    __builtin_amdgcn_sched_barrier(0);
    if (cb + 1 < nchunks) stage_sin(cb + 1, (cb + 1) & 1);  // ~3/4 chunk to land
    __builtin_amdgcn_sched_barrier(0);
    __builtin_amdgcn_s_setprio(1);
#pragma unroll
    for (int s_ = P1; s_ < NT; ++s_) TAP_ONE(s_)
    __builtin_amdgcn_s_setprio(0);
  }
#undef TAP_ONE

  // ---- epilogue: bias (+ parity packing for masked) ----
  float* outp = P.out + cd.out_off;
#define EPI_U(A, OT, PT)                                                        \
  {                                                                             \
    int h = hblk + wid;                                                         \
    _Pragma("unroll")                                                           \
    for (int r = 0; r < 16; ++r) {                                              \
      int row = (r & 3) + ((r >> 2) << 3) + (kq << 2);                          \
      int oc = (mb << 6) + ((OT) << 5) + row;                                   \
      outp[(size_t)(b * cd.OC + oc) * 4096 + (h << 6) + ((PT) << 5) + l31] =    \
          (A)[r] + cd.bias[oc];                                                 \
    }                                                                           \
  }
#define EPI_M(A, OT, PT)                                                        \
  {                                                                             \
    int h = hblk + (wid << 1) + (PT);                                           \
    _Pragma("unroll")                                                           \
    for (int r = 0; r < 16; ++r) {                                              \
      int row = (r & 3) + ((r >> 2) << 3) + (kq << 2);                          \
      int oc = (mb << 6) + ((OT) << 5) + row;                                   \
      float val = (A)[r] + cd.bias[oc];                                         \
      float2 pr;                                                                \
      if ((PT) == 0) { pr.x = 0.0f; pr.y = val; }                               \
      else           { pr.x = val;  pr.y = 0.0f; }                              \
      *(float2*)(outp + (size_t)(b * cd.OC + oc) * 4096 + (h << 6) + (l31 << 1)) = pr; \
    }                                                                           \
  }
  if (!MASKED) {
    EPI_U(acc00, 0, 0); EPI_U(acc01, 0, 1);
    if (octmax > 1) { EPI_U(acc10, 1, 0); EPI_U(acc11, 1, 1); }
  } else {
    EPI_M(acc00, 0, 0); EPI_M(acc01, 0, 1);
    if (octmax > 1) { EPI_M(acc10, 1, 0); EPI_M(acc11, 1, 1); }
  }
#undef EPI_U
#undef EPI_M
}

__global__ __launch_bounds__(256, 3) void k_conv_main(MainParams P) {
  __shared__ bf16_t S[18432];   // 36864 B: 2 x (2 icg planes x 9 groups) unmasked max
  int bid = blockIdx.x;
  int ci = 0;
#pragma unroll
  for (int i = 1; i < 9; ++i) if (bid >= P.cv[i].job_start) ci = i;
  ConvDesc cd = P.cv[ci];
  int local = bid - cd.job_start;
  if (cd.masked) conv_run<true>(cd, P, local, S);
  else           conv_run<false>(cd, P, local, S);
}

extern "C" void kernel_launch(void* const* d_in, const int* in_sizes, int n_in,
                              void* d_out, int out_size, void* d_ws, size_t ws_size,
                              hipStream_t stream) {
  const float* y = (const float*)d_in[0];
  bf16_t* yt  = (bf16_t*)d_ws;                               // 10,485,760 el
  bf16_t* ytp = yt + (size_t)NPIX * CTOT;                    // +5,242,880 el
  bf16_t* wt  = ytp + (size_t)(NPIX / 2) * CTOT;             // +3,660,800 el
  bf16_t* zp  = wt + 3660800;                                // +512 el (1 KB zeros)

  // Heaviest-first:      ch4      sp4     ch3     ch2     ch1     sp3     sp2     sp1    sp0
  static const int ICv[9]  = {128,    192,    64,     32,     16,     64,     32,     16,    16};
  static const int OCv[9]  = {384,    384,    128,    64,     32,     128,    64,     32,    32};
  static const int OCp[9]  = {384,    384,    128,    64,     64,     128,    64,     64,    64};
  static const int WIDX[9] = {19,     11,     17,     15,     13,     9,      7,      5,     3};
  static const int BIDX[9] = {20,     12,     18,     16,     14,     10,     8,      6,     4};
  static const int CHS[9]  = {0,      128,    0,      0,      0,      64,     32,     16,    0};
  static const int MSK[9]  = {0,      1,      0,      0,      0,      1,      1,      1,     1};
  static const int WTOFF[9] = {0, 1228800, 3072000, 3276800, 3328000,
                               3353600, 3558400, 3609600, 3635200};
  static const int OUTOFF[9] = {28311552, 15728640, 11534336, 5242880, 2097152,
                                7340032,  3145728,  1048576,  0};
  // blocks: unmasked (OCp/64)*128, masked (OCp/64)*64
  static const int JOBST[9] = {0, 768, 1152, 1408, 1536, 1664, 1792, 1856, 1920};  // total 1984
  // prep weight-block starts
  static const int PJST[9] = {0, 192, 480, 512, 520, 524, 556, 564, 568};   // total 572

  PrepParams Q;
  Q.y = y; Q.yt = yt; Q.ytp = ytp; Q.wt = wt; Q.zp = (uint4*)zp;
  for (int i = 0; i < 9; ++i) {
    Q.w[i] = (const float*)d_in[WIDX[i]];
    Q.IC[i] = ICv[i]; Q.OC[i] = OCv[i]; Q.OCp[i] = OCp[i];
    Q.wtoff[i] = WTOFF[i]; Q.jst[i] = PJST[i];
  }
  k_prep<<<3133, 256, 0, stream>>>(Q);   // 2560 y-blocks + 572 w-blocks + 1 zero

  MainParams P;
  P.yt = yt; P.ytp = ytp; P.wt = wt; P.zp = zp; P.out = (float*)d_out;
  for (int i = 0; i < 9; ++i) {
    P.cv[i].bias = (const float*)d_in[BIDX[i]];
    P.cv[i].out_off = OUTOFF[i];
    P.cv[i].wt_off = WTOFF[i];
    P.cv[i].IC = ICv[i]; P.cv[i].OC = OCv[i]; P.cv[i].OCp = OCp[i];
    P.cv[i].chs = CHS[i]; P.cv[i].masked = MSK[i];
    P.cv[i].job_start = JOBST[i];
  }
  k_conv_main<<<1984, 256, 0, stream>>>(P);
}

// Round 14
// 173.921 us; speedup vs baseline: 1.5331x; 1.5331x over previous
//
#include <hip/hip_runtime.h>

typedef __bf16 bf16_t;
typedef __bf16 bf16x8 __attribute__((ext_vector_type(8)));
typedef float f32x16 __attribute__((ext_vector_type(16)));
typedef unsigned int u32;

#define CTOT 320
#define NPIX 32768  // 8*64*64

// global -> LDS direct DMA, 16 B per lane; LDS dest = wave-uniform base + lane*16
__device__ __forceinline__ void gload16(const void* g, void* l) {
  __builtin_amdgcn_global_load_lds((const __attribute__((address_space(1))) u32*)g,
                                   (__attribute__((address_space(3))) u32*)l, 16, 0, 0);
}

// ---------- merged prep: y transpose (+packed), 9 weight transposes, zero page
struct PrepParams {
  const float* y;
  bf16_t *yt, *ytp, *wt;
  const float* w[9];
  int IC[9], OC[9], OCp[9], wtoff[9], jst[9];
  uint4* zp;
};

__global__ __launch_bounds__(256) void k_prep(PrepParams Q) {
  int blk = blockIdx.x, tid = threadIdx.x;
  if (blk >= 2560) {
    int wb = blk - 2560;
    if (wb >= 572) { if (tid < 64) Q.zp[tid] = uint4{0u, 0u, 0u, 0u}; return; }
    int ci = 0;
#pragma unroll
    for (int i = 1; i < 9; ++i) if (wb >= Q.jst[i]) ci = i;
    int IC = Q.IC[ci], OCp = Q.OCp[ci], OC = Q.OC[ci];
    int idx = (wb - Q.jst[ci]) * 256 + tid;
    if (idx >= OCp * IC) return;
    int oc = idx / IC, ic = idx - oc * IC;
    bool valid = (oc < OC);
    const float* src = Q.w[ci] + (size_t)(oc * IC + ic) * 25;
    bf16_t* dst = Q.wt + Q.wtoff[ci];
    int icg = ic >> 3, ie = ic & 7;
#pragma unroll
    for (int t = 0; t < 25; ++t) {
      float v = valid ? src[t] : 0.0f;
      dst[(size_t)((t * (IC >> 3) + icg) * OCp + oc) * 8 + ie] = (bf16_t)v;
    }
    return;
  }
  __shared__ bf16_t T[64][72];
  int c0 = (blk % 5) * 64;
  int bh = blk / 5;
  int b = bh >> 6, h = bh & 63;
  {
    int c = tid >> 2, w0 = (tid & 3) << 4;
    const float* src = Q.y + (size_t)(b * CTOT + c0 + c) * 4096 + (h << 6) + w0;
#pragma unroll
    for (int j = 0; j < 16; j += 4) {
      float4 v = *(const float4*)(src + j);
      T[c][w0 + j + 0] = (bf16_t)v.x;
      T[c][w0 + j + 1] = (bf16_t)v.y;
      T[c][w0 + j + 2] = (bf16_t)v.z;
      T[c][w0 + j + 3] = (bf16_t)v.w;
    }
  }
  __syncthreads();
  {
    int w = tid >> 2, cq = (tid & 3) << 4;
    union { uint4 v; bf16_t b[8]; } u0, u1;
#pragma unroll
    for (int j = 0; j < 8; ++j) { u0.b[j] = T[cq + j][w]; u1.b[j] = T[cq + 8 + j][w]; }
    bf16_t* dst = Q.yt + (size_t)((bh << 6) | w) * CTOT + c0 + cq;
    *(uint4*)dst = u0.v;
    *(uint4*)(dst + 8) = u1.v;
  }
  if (tid < 128) {  // packed even-checkerboard copy: w = 2j + (h&1)
    int j = tid >> 2, cq = (tid & 3) << 4;
    int w = (j << 1) + (h & 1);
    union { uint4 v; bf16_t b[8]; } u0, u1;
#pragma unroll
    for (int k = 0; k < 8; ++k) { u0.b[k] = T[cq + k][w]; u1.b[k] = T[cq + 8 + k][w]; }
    bf16_t* dst = Q.ytp + (size_t)((bh << 5) + j) * CTOT + c0 + cq;
    *(uint4*)dst = u0.v;
    *(uint4*)(dst + 8) = u1.v;
  }
}

// ---------- main conv: 32x32x16 MFMA, K-chunk=16, wave tile 64oc x 128px
// (2 A-reads + 4 B-reads per 8 MFMAs = 0.75 ds_read/MFMA), Sw in LDS (grouped,
// alternating buffers), Sin double-buffered, all staging via global_load_lds.
struct ConvDesc {
  const float* bias;
  int out_off, wt_off;
  int IC, OC, OCp, chs, masked, job_start;
};
struct MainParams {
  const bf16_t* yt;
  const bf16_t* ytp;
  const bf16_t* wt;
  const bf16_t* zp;
  float* out;
  ConvDesc cv[9];
};

template <bool MASKED>
__device__ __forceinline__ void conv_run(const ConvDesc cd, const MainParams& P,
                                         int local, bf16_t* S) {
  constexpr int NT   = MASKED ? 12 : 25;
  constexpr int COLS = MASKED ? 36 : 68;
  constexpr int REAL = MASKED ? 720 : 816;   // 20x36 / 12x68 pixel slots
  constexpr int NSG  = MASKED ? 12 : 13;     // 64-slot DMA groups per plane
  constexpr int SPL  = NSG * 512;
  constexpr int SINB = 2 * SPL;
  constexpr int SWO  = 2 * SINB;

  // unmasked: block = 64oc x 512px (8 rows); masked: 64oc x 512ppx (16 out-rows)
  int mb = MASKED ? (local >> 5) : (local >> 6);
  int nb = local & (MASKED ? 31 : 63);
  int b  = MASKED ? (nb >> 2) : (nb >> 3);
  int hblk = MASKED ? ((nb & 3) << 4) : ((nb & 7) << 3);
  int tid = threadIdx.x, lane = tid & 63, wid = tid >> 6;
  int l31 = lane & 31, kq = lane >> 5;

  int octmax = (cd.OC - (mb << 6)) >> 5; if (octmax > 2) octmax = 2;

  f32x16 acc0[4] = {}, acc1[4] = {};   // [nf]; acc1 used when octmax>1

  int aofs = SWO + kq * 512 + l31 * 8;
  // wave covers: unmasked rows (wid*2, wid*2+1) x 64 cols; masked packed rows wid*4..+3
  int bofs = kq * SPL + (MASKED ? (((wid << 2) * 36 + 1 + l31) * 8)
                                : (((wid << 1) * 68 + l31) * 8));

  const bf16_t* wtc = P.wt + cd.wt_off;
  int icgs = cd.IC >> 3;
  int nchunks = cd.IC >> 4;

  auto stage_sin = [&](int cb, int buf) {
    int ic0 = cb << 4;
    for (int g = wid; g < 2 * NSG; g += 4) {
      int p = (g >= NSG) ? 1 : 0;
      int gi = g - p * NSG;
      int s = (gi << 6) + lane;
      int rr = s / COLS, cc = s - rr * COLS;
      int h = hblk + rr - 2;
      const bf16_t* gp;
      if (!MASKED) {
        int w = cc - 2;
        bool inb = (s < REAL) && ((unsigned)h < 64u) && ((unsigned)w < 64u);
        gp = inb ? (P.yt + (size_t)((((b << 6) + (h & 63)) << 6) | (w & 63)) * CTOT
                        + cd.chs + ic0 + (p << 3))
                 : P.zp;
      } else {
        int j = cc - 1;
        bool inb = (s < REAL) && ((unsigned)h < 64u) && ((unsigned)j < 32u);
        gp = inb ? (P.ytp + (size_t)((((b << 6) + (h & 63)) << 5) + (j & 31)) * CTOT
                         + cd.chs + ic0 + (p << 3))
                 : P.zp;
      }
      gload16(gp, S + buf * SINB + p * SPL + (gi << 9));
    }
  };
  auto stage_sw = [&](int gstart, int gcnt, int swb, int cb) {
    int ic0 = cb << 4;
    for (int t = wid; t < 2 * gcnt; t += 4) {
      int slot = t >> 1, icg = t & 1;
      int ti = gstart + slot;
      int tap = MASKED ? (2 * ti + 1) : ti;
      const bf16_t* gp = wtc +
          (size_t)((tap * icgs + (ic0 >> 3) + icg) * cd.OCp + (mb << 6) + lane) * 8;
      gload16(gp, S + SWO + ((swb * 7 + slot) << 10) + (icg << 9));
    }
  };

#define TAP_ONE(TI, SL)                                                         \
    {                                                                           \
      int tap_ = MASKED ? (2 * (TI) + 1) : (TI);                                \
      int dy_ = tap_ / 5, dx_ = tap_ % 5;                                       \
      const bf16_t* sw_ = S + aofs + (SL) * 1024;                               \
      bf16x8 af0 = *(const bf16x8*)sw_;                                         \
      bf16x8 af1 = {};                                                          \
      if (octmax > 1) af1 = *(const bf16x8*)(sw_ + 256);                        \
      _Pragma("unroll")                                                         \
      for (int nf = 0; nf < 4; ++nf) {                                          \
        int ro_;                                                                \
        if (!MASKED) {                                                          \
          ro_ = ((((nf >> 1) + dy_) * 68) + ((nf & 1) << 5) + dx_) * 8;         \
        } else {                                                                \
          int joff_ = ((nf & 1) == 0) ? (dx_ - 1 - (dy_ & 1)) / 2               \
                                      : (dx_ - 2 - ((dy_ + 1) & 1)) / 2;        \
          ro_ = ((nf + dy_) * 36 + joff_) * 8;                                  \
        }                                                                       \
        bf16x8 bv = *(const bf16x8*)(Sn + bofs + ro_);                          \
        acc0[nf] = __builtin_amdgcn_mfma_f32_32x32x16_bf16(af0, bv, acc0[nf], 0, 0, 0); \
        if (octmax > 1)                                                         \
          acc1[nf] = __builtin_amdgcn_mfma_f32_32x32x16_bf16(af1, bv, acc1[nf], 0, 0, 0); \
      }                                                                         \
    }
#define RUNG(GS, SB, CNT)                                                       \
    __builtin_amdgcn_s_setprio(1);                                              \
    _Pragma("unroll")                                                           \
    for (int s_ = 0; s_ < (CNT); ++s_) TAP_ONE((GS) + s_, (SB) + s_)            \
    __builtin_amdgcn_s_setprio(0);

  stage_sin(0, 0);
  stage_sw(0, MASKED ? 6 : 7, 0, 0);
  for (int cb = 0; cb < nchunks; ++cb) {
    const bf16_t* Sn = S + (cb & 1) * SINB;
    __syncthreads();                      // drains Sin(cb) + G0(cb)
    if (!MASKED) {
      stage_sw(7, 6, 1, cb);              // G1 -> slots 7..12 (lands under G0)
      RUNG(0, 0, 7)
      __syncthreads();                    // drains G1
      stage_sw(13, 6, 0, cb);             // G2 -> slots 0..5
      RUNG(7, 7, 6)
      __syncthreads();                    // drains G2
      stage_sw(19, 6, 1, cb);             // G3 -> slots 7..12
      RUNG(13, 0, 6)
      __syncthreads();                    // drains G3
      if (cb + 1 < nchunks) {
        stage_sin(cb + 1, (cb + 1) & 1);  // ~7 taps to land (drained next top)
        stage_sw(0, 7, 0, cb + 1);        // G0'
      }
      RUNG(19, 7, 6)
    } else {
      stage_sw(6, 6, 1, cb);              // G1 -> slots 7..12
      RUNG(0, 0, 6)
      __syncthreads();                    // drains G1
      if (cb + 1 < nchunks) {
        stage_sin(cb + 1, (cb + 1) & 1);
        stage_sw(0, 6, 0, cb + 1);
      }
      RUNG(6, 7, 6)
    }
  }
#undef RUNG
#undef TAP_ONE

  // ---- epilogue: bias (+ parity packing for masked) ----
  float* outp = P.out + cd.out_off;
#define EPI_U(A, OT, NF)                                                        \
  {                                                                             \
    int h = hblk + (wid << 1) + ((NF) >> 1);                                    \
    int wc = (((NF) & 1) << 5) + l31;                                           \
    _Pragma("unroll")                                                           \
    for (int r = 0; r < 16; ++r) {                                              \
      int row = (r & 3) + ((r >> 2) << 3) + (kq << 2);                          \
      int oc = (mb << 6) + ((OT) << 5) + row;                                   \
      outp[(size_t)(b * cd.OC + oc) * 4096 + (h << 6) + wc] = (A)[r] + cd.bias[oc]; \
    }                                                                           \
  }
#define EPI_M(A, OT, NF)                                                        \
  {                                                                             \
    int h = hblk + (wid << 2) + (NF);                                           \
    _Pragma("unroll")                                                           \
    for (int r = 0; r < 16; ++r) {                                              \
      int row = (r & 3) + ((r >> 2) << 3) + (kq << 2);                          \
      int oc = (mb << 6) + ((OT) << 5) + row;                                   \
      float val = (A)[r] + cd.bias[oc];                                         \
      float2 pr;                                                                \
      if (((NF) & 1) == 0) { pr.x = 0.0f; pr.y = val; }                         \
      else                 { pr.x = val;  pr.y = 0.0f; }                        \
      *(float2*)(outp + (size_t)(b * cd.OC + oc) * 4096 + (h << 6) + (l31 << 1)) = pr; \
    }                                                                           \
  }
  if (!MASKED) {
#pragma unroll
    for (int nf = 0; nf < 4; ++nf) EPI_U(acc0[nf], 0, nf)
    if (octmax > 1) {
#pragma unroll
      for (int nf = 0; nf < 4; ++nf) EPI_U(acc1[nf], 1, nf)
    }
  } else {
#pragma unroll
    for (int nf = 0; nf < 4; ++nf) EPI_M(acc0[nf], 0, nf)
    if (octmax > 1) {
#pragma unroll
      for (int nf = 0; nf < 4; ++nf) EPI_M(acc1[nf], 1, nf)
    }
  }
#undef EPI_U
#undef EPI_M
}

__global__ __launch_bounds__(256, 2) void k_conv_main(MainParams P) {
  // unmasked: Sin dbuf 2*13312 + Sw 13*1024 = 39936 el = 79872 B -> 2 blocks/CU
  __shared__ bf16_t S[39936];
  int bid = blockIdx.x;
  int ci = 0;
#pragma unroll
  for (int i = 1; i < 9; ++i) if (bid >= P.cv[i].job_start) ci = i;
  ConvDesc cd = P.cv[ci];
  int local = bid - cd.job_start;
  if (cd.masked) conv_run<true>(cd, P, local, S);
  else           conv_run<false>(cd, P, local, S);
}

extern "C" void kernel_launch(void* const* d_in, const int* in_sizes, int n_in,
                              void* d_out, int out_size, void* d_ws, size_t ws_size,
                              hipStream_t stream) {
  const float* y = (const float*)d_in[0];
  bf16_t* yt  = (bf16_t*)d_ws;                               // 10,485,760 el
  bf16_t* ytp = yt + (size_t)NPIX * CTOT;                    // +5,242,880 el
  bf16_t* wt  = ytp + (size_t)(NPIX / 2) * CTOT;             // +3,660,800 el
  bf16_t* zp  = wt + 3660800;                                // +512 el (1 KB zeros)

  // Heaviest-first:      ch4      sp4     ch3     ch2     ch1     sp3     sp2     sp1    sp0
  static const int ICv[9]  = {128,    192,    64,     32,     16,     64,     32,     16,    16};
  static const int OCv[9]  = {384,    384,    128,    64,     32,     128,    64,     32,    32};
  static const int OCp[9]  = {384,    384,    128,    64,     64,     128,    64,     64,    64};
  static const int WIDX[9] = {19,     11,     17,     15,     13,     9,      7,      5,     3};
  static const int BIDX[9] = {20,     12,     18,     16,     14,     10,     8,      6,     4};
  static const int CHS[9]  = {0,      128,    0,      0,      0,      64,     32,     16,    0};
  static const int MSK[9]  = {0,      1,      0,      0,      0,      1,      1,      1,     1};
  static const int WTOFF[9] = {0, 1228800, 3072000, 3276800, 3328000,
                               3353600, 3558400, 3609600, 3635200};
  static const int OUTOFF[9] = {28311552, 15728640, 11534336, 5242880, 2097152,
                                7340032,  3145728,  1048576,  0};
  // blocks: unmasked (OCp/64)*64, masked (OCp/64)*32
  static const int JOBST[9] = {0, 384, 576, 704, 768, 832, 896, 928, 960};  // total 992
  static const int PJST[9] = {0, 192, 480, 512, 520, 524, 556, 564, 568};   // total 572

  PrepParams Q;
  Q.y = y; Q.yt = yt; Q.ytp = ytp; Q.wt = wt; Q.zp = (uint4*)zp;
  for (int i = 0; i < 9; ++i) {
    Q.w[i] = (const float*)d_in[WIDX[i]];
    Q.IC[i] = ICv[i]; Q.OC[i] = OCv[i]; Q.OCp[i] = OCp[i];
    Q.wtoff[i] = WTOFF[i]; Q.jst[i] = PJST[i];
  }
  k_prep<<<3133, 256, 0, stream>>>(Q);   // 2560 y-blocks + 572 w-blocks + 1 zero

  MainParams P;
  P.yt = yt; P.ytp = ytp; P.wt = wt; P.zp = zp; P.out = (float*)d_out;
  for (int i = 0; i < 9; ++i) {
    P.cv[i].bias = (const float*)d_in[BIDX[i]];
    P.cv[i].out_off = OUTOFF[i];
    P.cv[i].wt_off = WTOFF[i];
    P.cv[i].IC = ICv[i]; P.cv[i].OC = OCv[i]; P.cv[i].OCp = OCp[i];
    P.cv[i].chs = CHS[i]; P.cv[i].masked = MSK[i];
    P.cv[i].job_start = JOBST[i];
  }
  k_conv_main<<<992, 256, 0, stream>>>(P);
}

// Round 15
// 157.766 us; speedup vs baseline: 1.6901x; 1.1024x over previous
//
#include <hip/hip_runtime.h>

typedef __bf16 bf16_t;
typedef __bf16 bf16x8 __attribute__((ext_vector_type(8)));
typedef float f32x16 __attribute__((ext_vector_type(16)));
typedef unsigned int u32;

#define CTOT 320
#define NPIX 32768  // 8*64*64

// global -> LDS direct DMA, 16 B per lane; LDS dest = wave-uniform base + lane*16
__device__ __forceinline__ void gload16(const void* g, void* l) {
  __builtin_amdgcn_global_load_lds((const __attribute__((address_space(1))) u32*)g,
                                   (__attribute__((address_space(3))) u32*)l, 16, 0, 0);
}

// ---------- merged prep: y transpose (+packed), 9 weight transposes, zero page
struct PrepParams {
  const float* y;
  bf16_t *yt, *ytp, *wt;
  const float* w[9];
  int IC[9], OC[9], OCp[9], wtoff[9], jst[9];
  uint4* zp;
};

__global__ __launch_bounds__(256) void k_prep(PrepParams Q) {
  int blk = blockIdx.x, tid = threadIdx.x;
  if (blk >= 2560) {
    int wb = blk - 2560;
    if (wb >= 572) { if (tid < 64) Q.zp[tid] = uint4{0u, 0u, 0u, 0u}; return; }
    int ci = 0;
#pragma unroll
    for (int i = 1; i < 9; ++i) if (wb >= Q.jst[i]) ci = i;
    int IC = Q.IC[ci], OCp = Q.OCp[ci], OC = Q.OC[ci];
    int idx = (wb - Q.jst[ci]) * 256 + tid;
    if (idx >= OCp * IC) return;
    int oc = idx / IC, ic = idx - oc * IC;
    bool valid = (oc < OC);
    const float* src = Q.w[ci] + (size_t)(oc * IC + ic) * 25;
    bf16_t* dst = Q.wt + Q.wtoff[ci];
    int icg = ic >> 3, ie = ic & 7;
#pragma unroll
    for (int t = 0; t < 25; ++t) {
      float v = valid ? src[t] : 0.0f;
      dst[(size_t)((t * (IC >> 3) + icg) * OCp + oc) * 8 + ie] = (bf16_t)v;
    }
    return;
  }
  __shared__ bf16_t T[64][72];
  int c0 = (blk % 5) * 64;
  int bh = blk / 5;
  int b = bh >> 6, h = bh & 63;
  {
    int c = tid >> 2, w0 = (tid & 3) << 4;
    const float* src = Q.y + (size_t)(b * CTOT + c0 + c) * 4096 + (h << 6) + w0;
#pragma unroll
    for (int j = 0; j < 16; j += 4) {
      float4 v = *(const float4*)(src + j);
      T[c][w0 + j + 0] = (bf16_t)v.x;
      T[c][w0 + j + 1] = (bf16_t)v.y;
      T[c][w0 + j + 2] = (bf16_t)v.z;
      T[c][w0 + j + 3] = (bf16_t)v.w;
    }
  }
  __syncthreads();
  {
    int w = tid >> 2, cq = (tid & 3) << 4;
    union { uint4 v; bf16_t b[8]; } u0, u1;
#pragma unroll
    for (int j = 0; j < 8; ++j) { u0.b[j] = T[cq + j][w]; u1.b[j] = T[cq + 8 + j][w]; }
    bf16_t* dst = Q.yt + (size_t)((bh << 6) | w) * CTOT + c0 + cq;
    *(uint4*)dst = u0.v;
    *(uint4*)(dst + 8) = u1.v;
  }
  if (tid < 128) {  // packed even-checkerboard copy: w = 2j + (h&1)
    int j = tid >> 2, cq = (tid & 3) << 4;
    int w = (j << 1) + (h & 1);
    union { uint4 v; bf16_t b[8]; } u0, u1;
#pragma unroll
    for (int k = 0; k < 8; ++k) { u0.b[k] = T[cq + k][w]; u1.b[k] = T[cq + 8 + k][w]; }
    bf16_t* dst = Q.ytp + (size_t)((bh << 5) + j) * CTOT + c0 + cq;
    *(uint4*)dst = u0.v;
    *(uint4*)(dst + 8) = u1.v;
  }
}

// ---------- main conv: 32x32x16 MFMA, K-chunk=16. Sw in 3 rotating 4-slot
// buffers staged 2 groups ahead with counted vmcnt(2) (never drains to 0 in
// the loop); Sin double-buffered, full-chunk window, one vmcnt(0)/chunk.
struct ConvDesc {
  const float* bias;
  int out_off, wt_off;
  int IC, OC, OCp, chs, masked, job_start;
};
struct MainParams {
  const bf16_t* yt;
  const bf16_t* ytp;
  const bf16_t* wt;
  const bf16_t* zp;
  float* out;
  ConvDesc cv[9];
};

template <bool MASKED>
__device__ __forceinline__ void conv_run(const ConvDesc cd, const MainParams& P,
                                         int local, bf16_t* S) {
  constexpr int NT   = MASKED ? 12 : 25;
  constexpr int NG   = MASKED ? 3 : 7;       // groups of <=4 taps per chunk
  constexpr int COLS = MASKED ? 36 : 68;
  constexpr int REAL = MASKED ? 720 : 816;
  constexpr int NSG  = MASKED ? 12 : 13;
  constexpr int SPL  = NSG * 512;
  constexpr int SINB = 2 * SPL;
  constexpr int SWO  = 2 * SINB;             // Sw region: 3 bufs x 4 slots x 1024 el

  int mb = MASKED ? (local >> 5) : (local >> 6);
  int nb = local & (MASKED ? 31 : 63);
  int b  = MASKED ? (nb >> 2) : (nb >> 3);
  int hblk = MASKED ? ((nb & 3) << 4) : ((nb & 7) << 3);
  int tid = threadIdx.x, lane = tid & 63, wid = tid >> 6;
  int l31 = lane & 31, kq = lane >> 5;
  bool sin_role = (wid < 4);   // waves 0-3: Sin DMA; waves 4-7: Sw DMA

  int octmax = (cd.OC - (mb << 6)) >> 5; if (octmax > 2) octmax = 2;

  f32x16 acc00 = {}, acc01 = {}, acc10 = {}, acc11 = {};

  int swoc = SWO + kq * 512 + l31 * 8;       // A-read base (+ rotating swR)
  int bofs = kq * SPL + (MASKED ? (((wid << 1) * 36 + 1 + l31) * 8)
                                : ((wid * 68 + l31) * 8));

  const bf16_t* wtc = P.wt + cd.wt_off;
  int icgs = cd.IC >> 3;
  int nchunks = cd.IC >> 4;

  // Sin staging: waves 0-3 only (their vmcnt holds ONLY Sin loads)
  auto stage_sin = [&](int cb, int buf) {
    int ic0 = cb << 4;
    for (int g = wid; g < 2 * NSG; g += 4) {
      int p = (g >= NSG) ? 1 : 0;
      int gi = g - p * NSG;
      int s = (gi << 6) + lane;
      int rr = s / COLS, cc = s - rr * COLS;
      int h = hblk + rr - 2;
      const bf16_t* gp;
      if (!MASKED) {
        int w = cc - 2;
        bool inb = (s < REAL) && ((unsigned)h < 64u) && ((unsigned)w < 64u);
        gp = inb ? (P.yt + (size_t)((((b << 6) + (h & 63)) << 6) | (w & 63)) * CTOT
                        + cd.chs + ic0 + (p << 3))
                 : P.zp;
      } else {
        int j = cc - 1;
        bool inb = (s < REAL) && ((unsigned)h < 64u) && ((unsigned)j < 32u);
        gp = inb ? (P.ytp + (size_t)((((b << 6) + (h & 63)) << 5) + (j & 31)) * CTOT
                         + cd.chs + ic0 + (p << 3))
                 : P.zp;
      }
      gload16(gp, S + buf * SINB + p * SPL + (gi << 9));
    }
  };
  // Sw staging: waves 4-7, EXACTLY 2 DMA ops per wave per group (uniform ->
  // vmcnt(2) precisely means "previous group landed"). Group = 4 taps
  // (last unmasked group padded with duplicate tap-24 loads).
  auto stage_sw = [&](int cbn, int jn, int wbase) {
    int ic0 = cbn << 4;
    int t = wid - 4;
#pragma unroll
    for (int o2 = 0; o2 < 2; ++o2) {
      int o = t + o2 * 4;
      int slot = o >> 1, icg = o & 1;
      int ti = 4 * jn + slot; if (ti >= NT) ti = NT - 1;
      int tap = MASKED ? (2 * ti + 1) : ti;
      const bf16_t* gp = wtc +
          (size_t)((tap * icgs + (ic0 >> 3) + icg) * cd.OCp + (mb << 6) + lane) * 8;
      gload16(gp, S + SWO + wbase + (slot << 10) + (icg << 9));
    }
  };

#define TAP_ONE(TI, SL)                                                         \
    {                                                                           \
      int tap_ = MASKED ? (2 * (TI) + 1) : (TI);                                \
      int dy_ = tap_ / 5, dx_ = tap_ % 5;                                       \
      bf16x8 af0 = *(const bf16x8*)(swp + (SL) * 1024);                         \
      bf16x8 bf0, bf1;                                                          \
      if (!MASKED) {                                                            \
        int toff_ = (dy_ * 68 + dx_) * 8;                                       \
        bf0 = *(const bf16x8*)(Sn + bofs + toff_);                              \
        bf1 = *(const bf16x8*)(Sn + bofs + toff_ + 256);                        \
      } else {                                                                  \
        int j0_ = (dx_ - 1 - (dy_ & 1)) / 2;                                    \
        int j1_ = (dx_ - 2 - ((dy_ + 1) & 1)) / 2;                              \
        bf0 = *(const bf16x8*)(Sn + bofs + (dy_ * 36 + j0_) * 8);               \
        bf1 = *(const bf16x8*)(Sn + bofs + ((dy_ + 1) * 36 + j1_) * 8);         \
      }                                                                         \
      acc00 = __builtin_amdgcn_mfma_f32_32x32x16_bf16(af0, bf0, acc00, 0, 0, 0);\
      acc01 = __builtin_amdgcn_mfma_f32_32x32x16_bf16(af0, bf1, acc01, 0, 0, 0);\
      if (octmax > 1) {                                                         \
        bf16x8 af1 = *(const bf16x8*)(swp + (SL) * 1024 + 256);                 \
        acc10 = __builtin_amdgcn_mfma_f32_32x32x16_bf16(af1, bf0, acc10, 0,0,0);\
        acc11 = __builtin_amdgcn_mfma_f32_32x32x16_bf16(af1, bf1, acc11, 0,0,0);\
      }                                                                         \
    }

  // prologue: Sin(0) + Sw groups G0 -> buf0, G1 -> buf1
  if (sin_role) stage_sin(0, 0);
  else { stage_sw(0, 0, 0); stage_sw(0, 1, 4096); }
  int gcnt = 2, jN = 2, cbN = 0;             // next group (global) to issue
  if (jN >= NG) { jN -= NG; ++cbN; }
  int swW = 8192, swR = 0;                   // rotating write/read buffer bases
  int totG = nchunks * NG;

  for (int cb = 0; cb < nchunks; ++cb) {
    const bf16_t* Sn = S + (cb & 1) * SINB;
#pragma unroll
    for (int j = 0; j < NG; ++j) {
      if (sin_role) {
        if (j == 0) asm volatile("s_waitcnt vmcnt(0)" ::: "memory");
      } else {
        asm volatile("s_waitcnt vmcnt(2)" ::: "memory");
      }
      __builtin_amdgcn_sched_barrier(0);
      __builtin_amdgcn_s_barrier();
      __builtin_amdgcn_sched_barrier(0);
      if (j == 0 && sin_role && cb + 1 < nchunks) stage_sin(cb + 1, (cb + 1) & 1);
      if (!sin_role && gcnt < totG) stage_sw(cbN, jN, swW);
      ++gcnt; if (++jN == NG) { jN = 0; ++cbN; }
      swW = (swW == 8192) ? 0 : swW + 4096;

      const bf16_t* swp = S + swoc + swR;
      __builtin_amdgcn_s_setprio(1);
      if (!MASKED && j == 6) {
        TAP_ONE(24, 0)
      } else {
#pragma unroll
        for (int s_ = 0; s_ < 4; ++s_) TAP_ONE(4 * j + s_, s_)
      }
      __builtin_amdgcn_s_setprio(0);
      swR = (swR == 8192) ? 0 : swR + 4096;
    }
  }
#undef TAP_ONE

  // ---- epilogue: bias (+ parity packing for masked) ----
  float* outp = P.out + cd.out_off;
#define EPI_U(A, OT, PT)                                                        \
  {                                                                             \
    int h = hblk + wid;                                                         \
    _Pragma("unroll")                                                           \
    for (int r = 0; r < 16; ++r) {                                              \
      int row = (r & 3) + ((r >> 2) << 3) + (kq << 2);                          \
      int oc = (mb << 6) + ((OT) << 5) + row;                                   \
      outp[(size_t)(b * cd.OC + oc) * 4096 + (h << 6) + ((PT) << 5) + l31] =    \
          (A)[r] + cd.bias[oc];                                                 \
    }                                                                           \
  }
#define EPI_M(A, OT, PT)                                                        \
  {                                                                             \
    int h = hblk + (wid << 1) + (PT);                                           \
    _Pragma("unroll")                                                           \
    for (int r = 0; r < 16; ++r) {                                              \
      int row = (r & 3) + ((r >> 2) << 3) + (kq << 2);                          \
      int oc = (mb << 6) + ((OT) << 5) + row;                                   \
      float val = (A)[r] + cd.bias[oc];                                         \
      float2 pr;                                                                \
      if ((PT) == 0) { pr.x = 0.0f; pr.y = val; }                               \
      else           { pr.x = val;  pr.y = 0.0f; }                              \
      *(float2*)(outp + (size_t)(b * cd.OC + oc) * 4096 + (h << 6) + (l31 << 1)) = pr; \
    }                                                                           \
  }
  if (!MASKED) {
    EPI_U(acc00, 0, 0); EPI_U(acc01, 0, 1);
    if (octmax > 1) { EPI_U(acc10, 1, 0); EPI_U(acc11, 1, 1); }
  } else {
    EPI_M(acc00, 0, 0); EPI_M(acc01, 0, 1);
    if (octmax > 1) { EPI_M(acc10, 1, 0); EPI_M(acc11, 1, 1); }
  }
#undef EPI_U
#undef EPI_M
}

__global__ __launch_bounds__(512, 4) void k_conv_main(MainParams P) {
  // unmasked: Sin dbuf 2*13312 + Sw 12*1024 = 38912 el = 77824 B -> 2 blocks/CU
  __shared__ bf16_t S[38912];
  int bid = blockIdx.x;
  int ci = 0;
#pragma unroll
  for (int i = 1; i < 9; ++i) if (bid >= P.cv[i].job_start) ci = i;
  ConvDesc cd = P.cv[ci];
  int local = bid - cd.job_start;
  if (cd.masked) conv_run<true>(cd, P, local, S);
  else           conv_run<false>(cd, P, local, S);
}

extern "C" void kernel_launch(void* const* d_in, const int* in_sizes, int n_in,
                              void* d_out, int out_size, void* d_ws, size_t ws_size,
                              hipStream_t stream) {
  const float* y = (const float*)d_in[0];
  bf16_t* yt  = (bf16_t*)d_ws;                               // 10,485,760 el
  bf16_t* ytp = yt + (size_t)NPIX * CTOT;                    // +5,242,880 el
  bf16_t* wt  = ytp + (size_t)(NPIX / 2) * CTOT;             // +3,660,800 el
  bf16_t* zp  = wt + 3660800;                                // +512 el (1 KB zeros)

  // Heaviest-first:      ch4      sp4     ch3     ch2     ch1     sp3     sp2     sp1    sp0
  static const int ICv[9]  = {128,    192,    64,     32,     16,     64,     32,     16,    16};
  static const int OCv[9]  = {384,    384,    128,    64,     32,     128,    64,     32,    32};
  static const int OCp[9]  = {384,    384,    128,    64,     64,     128,    64,     64,    64};
  static const int WIDX[9] = {19,     11,     17,     15,     13,     9,      7,      5,     3};
  static const int BIDX[9] = {20,     12,     18,     16,     14,     10,     8,      6,     4};
  static const int CHS[9]  = {0,      128,    0,      0,      0,      64,     32,     16,    0};
  static const int MSK[9]  = {0,      1,      0,      0,      0,      1,      1,      1,     1};
  static const int WTOFF[9] = {0, 1228800, 3072000, 3276800, 3328000,
                               3353600, 3558400, 3609600, 3635200};
  static const int OUTOFF[9] = {28311552, 15728640, 11534336, 5242880, 2097152,
                                7340032,  3145728,  1048576,  0};
  static const int JOBST[9] = {0, 384, 576, 704, 768, 832, 896, 928, 960};  // total 992
  static const int PJST[9] = {0, 192, 480, 512, 520, 524, 556, 564, 568};   // total 572

  PrepParams Q;
  Q.y = y; Q.yt = yt; Q.ytp = ytp; Q.wt = wt; Q.zp = (uint4*)zp;
  for (int i = 0; i < 9; ++i) {
    Q.w[i] = (const float*)d_in[WIDX[i]];
    Q.IC[i] = ICv[i]; Q.OC[i] = OCv[i]; Q.OCp[i] = OCp[i];
    Q.wtoff[i] = WTOFF[i]; Q.jst[i] = PJST[i];
  }
  k_prep<<<3133, 256, 0, stream>>>(Q);   // 2560 y-blocks + 572 w-blocks + 1 zero

  MainParams P;
  P.yt = yt; P.ytp = ytp; P.wt = wt; P.zp = zp; P.out = (float*)d_out;
  for (int i = 0; i < 9; ++i) {
    P.cv[i].bias = (const float*)d_in[BIDX[i]];
    P.cv[i].out_off = OUTOFF[i];
    P.cv[i].wt_off = WTOFF[i];
    P.cv[i].IC = ICv[i]; P.cv[i].OC = OCv[i]; P.cv[i].OCp = OCp[i];
    P.cv[i].chs = CHS[i]; P.cv[i].masked = MSK[i];
    P.cv[i].job_start = JOBST[i];
  }
  k_conv_main<<<992, 512, 0, stream>>>(P);
}